// Round 1
// baseline (213.154 us; speedup 1.0000x reference)
//
#include <hip/hip_runtime.h>
#include <hip/hip_bf16.h>
#include <hip/hip_cooperative_groups.h>
#include <stdint.h>

namespace cg = cooperative_groups;

// B=2, C=256, H=W=D=16 -> N=4096, nh=8, dh=32. ALL float32 I/O.
// Reference dead code: x_sa path (top-k, index_sample, W_out, b_out, v_sa) — epa = x_ca only.
// Round 8: conv split-K 3->4 (512 blocks = exact 2/CU), out2 retiled 128co x 64n
// (256 blocks, 48KB LDS -> 3/CU), gn_reduce+final fused via cooperative grid sync
// (Y never materialized; conv sums carried in registers across the sync).

#define B_ 2
#define C_ 256
#define N_ 4096
#define NH 8
#define PADV 5832
#define CN  (C_*N_)
#define BCN (B_*CN)

typedef unsigned short u16;
typedef unsigned int   u32;

using frag16 = __attribute__((ext_vector_type(8))) short;
using f32x4  = __attribute__((ext_vector_type(4))) float;

__device__ __forceinline__ u16 f2bf(float f) {
    u32 u = __float_as_uint(f);
    u += 0x7fff + ((u >> 16) & 1);
    return (u16)(u >> 16);
}
__device__ __forceinline__ float bb(u16 h) { return __uint_as_float((u32)h << 16); }
__device__ __forceinline__ void gld16(const void* g, void* l) {
    __builtin_amdgcn_global_load_lds((const __attribute__((address_space(1))) u32*)g,
                                     (__attribute__((address_space(3))) u32*)l, 16, 0, 0);
}
__device__ __forceinline__ int padrow(int n) {
    int z = n >> 8, y = (n >> 4) & 15, x = n & 15;
    return (z + 1) * 324 + (y + 1) * 18 + (x + 1);
}

// ---- workspace (float units)
#define OFF_TB    0            // bf16 [B][768][N]; aliased by PKB after ca_apply
#define OFF_SP    3145728      // fp32 [B][NH][8][1024] score partials (dead after ca_apply)
#define OFF_XCAB  3670016      // bf16 [B][N][C] (dead after out2)
#define OFF_PKB   0            // bf16 [4][B][C][N] conv partials (alias TB/SP/XCAB, all dead)
#define OFF_ATTB  6291456      // bf16 [B][C][N]
#define OFF_ATTP  7340032      // bf16 [B][PADV][C]
#define OFF_WT2   8833024      // bf16 [27][co][ci]
#define OFF_W2B   9717760      // bf16 [c][c']
#define OFF_WQB   9750528      // bf16 [j][c], j<768
#define OFF_XT    9848832      // bf16 [B][N][C]
#define OFF_RSQ   10897408     // fp32 [B][512]
#define OFF_RED   10898432     // fp32 [B][2] atomic mean/var accumulators

// ================ merged prep ================
__global__ __launch_bounds__(256) void k_prep(const float* __restrict__ CW, const float* __restrict__ W2,
                                              const float* __restrict__ Wq, const float* __restrict__ X,
                                              u16* __restrict__ WT2, u16* __restrict__ W2B,
                                              u16* __restrict__ Wqb, u16* __restrict__ XT,
                                              u32* __restrict__ APz, float* __restrict__ RSQ,
                                              float* __restrict__ RED) {
    __shared__ __align__(16) float ls[6912];
    float (*ts)[33] = (float(*)[33])ls;
    float (*t64)[65] = (float(*)[65])ls;
    int blk = blockIdx.x, tid = threadIdx.x;
    if (blk < 256) {                                    // WT2[t][co][ci] = conv_w[co][ci][t]
        int co = blk;
        const float* src = CW + (size_t)co * 6912;
        for (int u = tid; u < 6912; u += 256) ls[u] = src[u];
        __syncthreads();
#pragma unroll
        for (int t = 0; t < 27; ++t)
            WT2[(((size_t)t * 256 + co) << 8) + tid] = f2bf(ls[tid * 27 + t]);
    } else if (blk < 320) {                             // W2B[c][p] = W2[p][c]
        int bi = blk - 256; int c0 = (bi & 7) * 32, p0 = (bi >> 3) * 32;
        int tx = tid & 31, ty = tid >> 5;
#pragma unroll
        for (int i = 0; i < 4; ++i) ts[ty + i * 8][tx] = W2[(size_t)(p0 + ty + i * 8) * 256 + c0 + tx];
        __syncthreads();
#pragma unroll
        for (int i = 0; i < 4; ++i) W2B[(size_t)(c0 + ty + i * 8) * 256 + p0 + tx] = f2bf(ts[tx][ty + i * 8]);
    } else if (blk < 512) {                             // Wqb[j][c] = Wq[c][j], j<768
        int bi = blk - 320; int c0 = (bi & 7) * 32, j0 = (bi >> 3) * 32;
        int tx = tid & 31, ty = tid >> 5;
#pragma unroll
        for (int i = 0; i < 4; ++i) ts[ty + i * 8][tx] = Wq[(size_t)(c0 + ty + i * 8) * 1024 + j0 + tx];
        __syncthreads();
#pragma unroll
        for (int i = 0; i < 4; ++i) Wqb[(size_t)(j0 + ty + i * 8) * 256 + c0 + tx] = f2bf(ts[tx][ty + i * 8]);
    } else if (blk < 1024) {                            // XT[b][n][c] = x[b][c][n], 64x64 tiles
        int idx = blk - 512;
        int n0 = (idx & 63) * 64, c0 = ((idx >> 6) & 3) * 64, b = idx >> 8;
        int tn = tid & 63, tc4 = tid >> 6;
        const float* Xb = X + (size_t)b * CN;
#pragma unroll
        for (int i = 0; i < 16; ++i) t64[tc4 + i * 4][tn] = Xb[(size_t)(c0 + tc4 + i * 4) * N_ + n0 + tn];
        __syncthreads();
        u16* Xo = XT + (size_t)b * N_ * C_;
#pragma unroll
        for (int i = 0; i < 16; ++i)
            Xo[(size_t)(n0 + tc4 + i * 4) * C_ + c0 + tn] = f2bf(t64[tn][tc4 + i * 4]);
    } else if (blk < 6856) {                            // zero ATTp
        APz[(size_t)(blk - 1024) * 256 + tid] = 0;
    } else {                                            // zero RSQ + RED
        ((float4*)RSQ)[tid] = make_float4(0.f, 0.f, 0.f, 0.f);
        if (tid == 0) ((float4*)RED)[0] = make_float4(0.f, 0.f, 0.f, 0.f);
    }
}

// ================ QKV MFMA, K=64 chunks + RSQ row-sumsq atomics ================
__global__ __launch_bounds__(256) void k_qkv_mfma(const u16* __restrict__ Wqb, const u16* __restrict__ XT,
                                                  u16* __restrict__ Tb, float* __restrict__ RSQ) {
    __shared__ __align__(16) u16 As[2][8192], Bs[2][8192];
    int n0 = blockIdx.x * 128, j0 = blockIdx.y * 128, b = blockIdx.z;
    int tid = threadIdx.x, lane = tid & 63, w = tid >> 6;
    int wm = w & 1, wn = w >> 1, qm = lane >> 4, lm = lane & 15;
    int srow = lane >> 3;
    int sperm = (((lane & 7) ^ srow) << 3);
    const u16* aB = Wqb + ((size_t)(j0 + w * 32 + srow) << 8) + sperm;
    const u16* bB = XT + ((size_t)(b * N_ + n0 + w * 32 + srow) << 8) + sperm;
    int rdp = ((lm & 7) << 3);
    f32x4 acc[4][4] = {};
    auto stg = [&](int p, int kc) {
#pragma unroll
        for (int i = 0; i < 4; ++i) {
            gld16(aB + i * 2048 + kc * 64, &As[p][w * 2048 + i * 512]);
            gld16(bB + i * 2048 + kc * 64, &Bs[p][w * 2048 + i * 512]);
        }
    };
    stg(0, 0);
#pragma unroll
    for (int kt = 0; kt < 4; ++kt) {
        int p = kt & 1;
        __syncthreads();
        if (kt < 3) stg(p ^ 1, kt + 1);
#pragma unroll
        for (int c2 = 0; c2 < 2; ++c2) {
            frag16 af[4], bf[4];
#pragma unroll
            for (int i = 0; i < 4; ++i)
                af[i] = *(const frag16*)&As[p][(wm * 64 + i * 16 + lm) * 64 + ((((c2 * 4 + qm) << 3) ^ rdp))];
#pragma unroll
            for (int j = 0; j < 4; ++j)
                bf[j] = *(const frag16*)&Bs[p][(wn * 64 + j * 16 + lm) * 64 + ((((c2 * 4 + qm) << 3) ^ rdp))];
#pragma unroll
            for (int i = 0; i < 4; ++i)
#pragma unroll
                for (int j = 0; j < 4; ++j)
                    acc[i][j] = __builtin_amdgcn_mfma_f32_16x16x32_bf16(af[i], bf[j], acc[i][j], 0, 0, 0);
        }
    }
    u16* To = Tb + ((size_t)b * 768 + j0 + wm * 64) * N_ + n0 + wn * 64;
#pragma unroll
    for (int i = 0; i < 4; ++i)
#pragma unroll
        for (int j = 0; j < 4; ++j)
#pragma unroll
            for (int r = 0; r < 4; ++r)
                To[(size_t)(i * 16 + qm * 4 + r) * N_ + j * 16 + lm] = f2bf(acc[i][j][r]);
    if (j0 < 512) {
#pragma unroll
        for (int i = 0; i < 4; ++i)
#pragma unroll
            for (int r = 0; r < 4; ++r) {
                float s = 0.f;
#pragma unroll
                for (int j = 0; j < 4; ++j) s += acc[i][j][r] * acc[i][j][r];
                s += __shfl_xor(s, 1); s += __shfl_xor(s, 2);
                s += __shfl_xor(s, 4); s += __shfl_xor(s, 8);
                if (lm == 0)
                    atomicAdd(&RSQ[b * 512 + j0 + wm * 64 + i * 16 + qm * 4 + r], s);
            }
    }
}

// ================ CA scores via MFMA: SP[b][h][ks][d*32+e] = sum_{k in slice} q[d][k] k[e][k] =====
__global__ __launch_bounds__(256) void k_ca_score(const u16* __restrict__ Tb, float* __restrict__ SP) {
    __shared__ __align__(16) u16 Qs[2][8192], Ks[2][8192];   // 32 rows x 256 u16, XOR-swizzled chunks
    int ks = blockIdx.x, h = blockIdx.y, b = blockIdx.z;
    int tid = threadIdx.x, lane = tid & 63, w = tid >> 6;
    int wm = w & 1, wn = w >> 1, qm = lane >> 4, lm = lane & 15;
    const u16* Qb = Tb + ((size_t)b * 768 + h * 32) * N_;
    const u16* Kb = Tb + ((size_t)b * 768 + 256 + h * 32) * N_;
    int k0base = ks * 512;
    auto stg = [&](int p, int ck) {
        int k0 = k0base + ck * 256;
#pragma unroll
        for (int ri = 0; ri < 4; ++ri) {
            int row = ri * 8 + w * 2 + (lane >> 5);
            int cg = (lane & 31) ^ (row & 31);
            gld16(Qb + (size_t)row * N_ + k0 + cg * 8, &Qs[p][ri * 2048 + w * 512]);
            gld16(Kb + (size_t)row * N_ + k0 + cg * 8, &Ks[p][ri * 2048 + w * 512]);
        }
    };
    f32x4 acc = {};
    stg(0, 0);
#pragma unroll
    for (int ck = 0; ck < 2; ++ck) {
        int p = ck & 1;
        __syncthreads();
        if (ck < 1) stg(p ^ 1, ck + 1);
        int rowA = wm * 16 + lm, rowB = wn * 16 + lm;
#pragma unroll
        for (int kk = 0; kk < 8; ++kk) {
            int slotA = ((kk * 4 + qm) ^ (rowA & 31)) << 3;
            int slotB = ((kk * 4 + qm) ^ (rowB & 31)) << 3;
            frag16 af = *(const frag16*)&Qs[p][rowA * 256 + slotA];
            frag16 bf = *(const frag16*)&Ks[p][rowB * 256 + slotB];
            acc = __builtin_amdgcn_mfma_f32_16x16x32_bf16(af, bf, acc, 0, 0, 0);
        }
    }
    float* o = SP + (((size_t)(b * NH + h)) * 8 + ks) * 1024;
#pragma unroll
    for (int r = 0; r < 4; ++r)
        o[(wm * 16 + qm * 4 + r) * 32 + wn * 16 + lm] = acc[r];
}

// ================ ca: combine partials, scale by 1/(||q|| ||k||), softmax, apply ================
__global__ __launch_bounds__(256) void k_ca_apply(const u16* __restrict__ Tb, const float* __restrict__ SP,
                                                  const float* __restrict__ RSQ, u16* __restrict__ XCAb) {
    int n0 = blockIdx.x * 256, h = blockIdx.y, b = blockIdx.z;
    __shared__ float raw[1024];
    __shared__ float Ae[32][32];
    __shared__ float sq[32], sk[32];
    int tid = threadIdx.x;
    const float* Sp = SP + ((size_t)(b * NH + h)) * 8192;
    for (int u = tid; u < 1024; u += 256) {
        float v = 0.f;
#pragma unroll
        for (int s = 0; s < 8; ++s) v += Sp[s * 1024 + u];
        raw[u] = v;
    }
    if (tid < 32) {
        sq[tid] = 1.0f / fmaxf(sqrtf(RSQ[b * 512 + h * 32 + tid]), 1e-12f);
        sk[tid] = 1.0f / fmaxf(sqrtf(RSQ[b * 512 + 256 + h * 32 + tid]), 1e-12f);
    }
    __syncthreads();
    if (tid < 32) {
        float iq = sq[tid];
        float sv[32]; float m = -1e30f;
#pragma unroll
        for (int e = 0; e < 32; ++e) { sv[e] = raw[tid * 32 + e] * iq * sk[e]; m = fmaxf(m, sv[e]); }
        float sm = 0.f;
#pragma unroll
        for (int e = 0; e < 32; ++e) { sv[e] = __expf(sv[e] - m); sm += sv[e]; }
        float rinv = 1.0f / sm;
#pragma unroll
        for (int e = 0; e < 32; ++e) Ae[e][tid] = sv[e] * rinv;
    }
    __syncthreads();
    int n = n0 + tid;
    const u16* V = Tb + ((size_t)b * 768 + 512 + h * 32) * N_ + n;
    float acc[32];
#pragma unroll
    for (int d = 0; d < 32; ++d) acc[d] = 0.f;
#pragma unroll
    for (int e = 0; e < 32; ++e) {
        float v = bb(V[(size_t)e * N_]);
#pragma unroll
        for (int dg = 0; dg < 8; ++dg) {
            float4 a4 = *(const float4*)&Ae[e][dg * 4];
            acc[dg * 4 + 0] += a4.x * v; acc[dg * 4 + 1] += a4.y * v;
            acc[dg * 4 + 2] += a4.z * v; acc[dg * 4 + 3] += a4.w * v;
        }
    }
    u16* o = XCAb + ((size_t)b * N_ + n) * C_ + h * 32;
#pragma unroll
    for (int dg = 0; dg < 8; ++dg) {
        ushort4 pk;
        pk.x = f2bf(acc[dg * 4 + 0]); pk.y = f2bf(acc[dg * 4 + 1]);
        pk.z = f2bf(acc[dg * 4 + 2]); pk.w = f2bf(acc[dg * 4 + 3]);
        *(ushort4*)(o + dg * 4) = pk;
    }
}

// ================ out2 MFMA (128co x 64n tiles, 256 blocks) + residual ================
__global__ __launch_bounds__(256) void k_out2_mfma(const u16* __restrict__ W2B, const u16* __restrict__ XCAb,
                                                   const float* __restrict__ bias2, const float* __restrict__ g1,
                                                   const float* __restrict__ X, u16* __restrict__ ATTb,
                                                   u16* __restrict__ ATTp) {
    __shared__ __align__(16) u16 As[2][8192], Bs[2][4096];
    int n0 = blockIdx.x * 64, c0 = blockIdx.y * 128, b = blockIdx.z;
    int tid = threadIdx.x, lane = tid & 63, w = tid >> 6;
    int wm = w & 1, wn = w >> 1, qm = lane >> 4, lm = lane & 15;
    int srow = lane >> 3;
    int sperm = (((lane & 7) ^ srow) << 3);
    const u16* aB = W2B + ((size_t)(c0 + w * 32 + srow) << 8) + sperm;
    const u16* bB = XCAb + ((size_t)(b * N_ + n0 + w * 16 + srow) << 8) + sperm;
    int rdp = ((lm & 7) << 3);
    f32x4 acc[4][2] = {};
    auto stg = [&](int p, int kc) {
#pragma unroll
        for (int i = 0; i < 4; ++i)
            gld16(aB + i * 2048 + kc * 64, &As[p][w * 2048 + i * 512]);
#pragma unroll
        for (int i = 0; i < 2; ++i)
            gld16(bB + i * 2048 + kc * 64, &Bs[p][w * 1024 + i * 512]);
    };
    stg(0, 0);
#pragma unroll
    for (int kt = 0; kt < 4; ++kt) {
        int p = kt & 1;
        __syncthreads();
        if (kt < 3) stg(p ^ 1, kt + 1);
#pragma unroll
        for (int c2 = 0; c2 < 2; ++c2) {
            frag16 af[4], bf[2];
#pragma unroll
            for (int i = 0; i < 4; ++i)
                af[i] = *(const frag16*)&As[p][(wm * 64 + i * 16 + lm) * 64 + ((((c2 * 4 + qm) << 3) ^ rdp))];
#pragma unroll
            for (int j = 0; j < 2; ++j)
                bf[j] = *(const frag16*)&Bs[p][(wn * 32 + j * 16 + lm) * 64 + ((((c2 * 4 + qm) << 3) ^ rdp))];
#pragma unroll
            for (int i = 0; i < 4; ++i)
#pragma unroll
                for (int j = 0; j < 2; ++j)
                    acc[i][j] = __builtin_amdgcn_mfma_f32_16x16x32_bf16(af[i], bf[j], acc[i][j], 0, 0, 0);
        }
    }
    int c_base = c0 + wm * 64, n_base = n0 + wn * 32;
    const float* xin = X + (size_t)b * CN;
    u16* Ao = ATTb + (size_t)b * CN;
    u16* Ap = ATTp + ((size_t)b * PADV << 8);
    float val[4][2][4];
#pragma unroll
    for (int i = 0; i < 4; ++i)
#pragma unroll
        for (int r = 0; r < 4; ++r) {
            int c = c_base + i * 16 + qm * 4 + r;
            float gv = g1[c], bi = bias2[c];
#pragma unroll
            for (int j = 0; j < 2; ++j) {
                int n = n_base + j * 16 + lm;
                float v = xin[(size_t)c * N_ + n] + gv * (acc[i][j][r] + bi);
                val[i][j][r] = v;
                Ao[(size_t)c * N_ + n] = f2bf(v);
            }
        }
#pragma unroll
    for (int j = 0; j < 2; ++j) {
        int n = n_base + j * 16 + lm;
        int pr = padrow(n);
#pragma unroll
        for (int i = 0; i < 4; ++i) {
            ushort4 pk;
            pk.x = f2bf(val[i][j][0]); pk.y = f2bf(val[i][j][1]);
            pk.z = f2bf(val[i][j][2]); pk.w = f2bf(val[i][j][3]);
            *(ushort4*)&Ap[((size_t)pr << 8) + c_base + i * 16 + qm * 4] = pk;
        }
    }
}

// ================ conv 3^3 MFMA, split-K=4 (chunk-level tap indexing), 512 blocks ================
__global__ __launch_bounds__(256) void k_conv_mfma(const u16* __restrict__ WT2, const u16* __restrict__ ATTp,
                                                   u16* __restrict__ Pk) {
    __shared__ __align__(16) u16 As[2][8192], Bs[2][8192];
    int n0 = blockIdx.x * 128;
    int co0 = (blockIdx.y & 1) * 128, ks = blockIdx.y >> 1;   // 4 K-slices of 27 chunks each
    int b = blockIdx.z;
    int tid = threadIdx.x, lane = tid & 63, w = tid >> 6;
    int wm = w & 1, wn = w >> 1, qm = lane >> 4, lm = lane & 15;
    int srow = lane >> 3;
    int sperm = (((lane & 7) ^ srow) << 3);
    int ks27 = ks * 27;
    const u16* aB = WT2 + (((size_t)co0 + w * 32 + srow) << 8) + sperm;
    int prA[4];
#pragma unroll
    for (int i = 0; i < 4; ++i) prA[i] = padrow(n0 + w * 32 + i * 8 + srow) << 8;
    const u16* bB = ATTp + ((size_t)b * PADV << 8) + sperm;
    int rdp = ((lm & 7) << 3);
    f32x4 acc[4][4] = {};
    auto stg = [&](int p, int kt) {
        int g = ks27 + kt;                  // global K-chunk in [0,108)
        int tap = g >> 2, kc = g & 3;       // tap in [0,27), 64-wide ci chunk
        int t9 = tap % 9;
        int Koff = (tap / 9 - 1) * 324 + (t9 / 3 - 1) * 18 + (t9 % 3 - 1);
#pragma unroll
        for (int i = 0; i < 4; ++i) {
            gld16(aB + (size_t)tap * 65536 + i * 2048 + kc * 64, &As[p][w * 2048 + i * 512]);
            gld16(bB + prA[i] + Koff * 256 + kc * 64,            &Bs[p][w * 2048 + i * 512]);
        }
    };
    stg(0, 0);
#pragma unroll
    for (int kt = 0; kt < 27; ++kt) {
        int p = kt & 1;
        __syncthreads();
        if (kt < 26) stg(p ^ 1, kt + 1);
#pragma unroll
        for (int c2 = 0; c2 < 2; ++c2) {
            frag16 af[4], bf[4];
#pragma unroll
            for (int i = 0; i < 4; ++i)
                af[i] = *(const frag16*)&As[p][(wm * 64 + i * 16 + lm) * 64 + ((((c2 * 4 + qm) << 3) ^ rdp))];
#pragma unroll
            for (int j = 0; j < 4; ++j)
                bf[j] = *(const frag16*)&Bs[p][(wn * 64 + j * 16 + lm) * 64 + ((((c2 * 4 + qm) << 3) ^ rdp))];
#pragma unroll
            for (int i = 0; i < 4; ++i)
#pragma unroll
                for (int j = 0; j < 4; ++j)
                    acc[i][j] = __builtin_amdgcn_mfma_f32_16x16x32_bf16(af[i], bf[j], acc[i][j], 0, 0, 0);
        }
    }
    u16* Pb = Pk + ((size_t)(ks * B_ + b) * C_ + co0 + wm * 64) * N_ + n0 + wn * 64;
#pragma unroll
    for (int i = 0; i < 4; ++i)
#pragma unroll
        for (int j = 0; j < 4; ++j)
#pragma unroll
            for (int r = 0; r < 4; ++r)
                Pb[(size_t)(i * 16 + qm * 4 + r) * N_ + j * 16 + lm] = f2bf(acc[i][j][r]);
}

// ================ fused: combine 4 split-K partials -> GN stats -> grid sync -> finalize ========
__global__ __launch_bounds__(256) void k_gnfinal(const u16* __restrict__ Pk, const u16* __restrict__ ATTb,
                                                 float* __restrict__ RED, const float* __restrict__ gw,
                                                 const float* __restrict__ gb, float* __restrict__ out) {
    int blk = blockIdx.x, b = blockIdx.y;
    size_t base = (size_t)b * CN + (size_t)blk * 16384;
    const u16* p0 = Pk + base;
    float vr[8][8];
    float s = 0.f, q = 0.f;
    int t8 = threadIdx.x * 8;
#pragma unroll
    for (int it = 0; it < 8; ++it) {
        int u = t8 + it * 2048;
        uint4 a0 = *(const uint4*)&p0[u];
        uint4 a1 = *(const uint4*)&p0[(size_t)BCN + u];
        uint4 a2 = *(const uint4*)&p0[(size_t)2 * BCN + u];
        uint4 a3 = *(const uint4*)&p0[(size_t)3 * BCN + u];
        const u16 *A = (const u16*)&a0, *B1 = (const u16*)&a1, *C2 = (const u16*)&a2, *D3 = (const u16*)&a3;
#pragma unroll
        for (int i = 0; i < 8; ++i) {
            float vv = bb(A[i]) + bb(B1[i]) + bb(C2[i]) + bb(D3[i]);
            vr[it][i] = vv; s += vv; q += vv * vv;
        }
    }
#pragma unroll
    for (int off = 32; off; off >>= 1) { s += __shfl_down(s, off); q += __shfl_down(q, off); }
    __shared__ float rs_[4], rq_[4];
    __shared__ float smu[2];
    int lane = threadIdx.x & 63, wv = threadIdx.x >> 6;
    if (!lane) { rs_[wv] = s; rq_[wv] = q; }
    __syncthreads();
    if (threadIdx.x == 0) {
        atomicAdd(&RED[b * 2 + 0], rs_[0] + rs_[1] + rs_[2] + rs_[3]);
        atomicAdd(&RED[b * 2 + 1], rq_[0] + rq_[1] + rq_[2] + rq_[3]);
    }
    cg::this_grid().sync();
    if (threadIdx.x == 0) {
        float ss = __hip_atomic_load(&RED[b * 2 + 0], __ATOMIC_RELAXED, __HIP_MEMORY_SCOPE_AGENT);
        float qq = __hip_atomic_load(&RED[b * 2 + 1], __ATOMIC_RELAXED, __HIP_MEMORY_SCOPE_AGENT);
        float inv = 1.0f / (float)CN;
        float mu = ss * inv, var = qq * inv - mu * mu;
        smu[0] = mu; smu[1] = rsqrtf(var + 1e-5f);
    }
    __syncthreads();
    float mu = smu[0], rin = smu[1];
#pragma unroll
    for (int it = 0; it < 8; ++it) {
        int u = t8 + it * 2048;
        size_t gi = base + u;
        int c = (int)((gi >> 12) & 255);
        float gwc = gw[c], gbc = gb[c];
        uint4 at = *(const uint4*)&ATTb[gi];
        const u16* Ab = (const u16*)&at;
        float ov[8];
#pragma unroll
        for (int i = 0; i < 8; ++i) {
            float y = (vr[it][i] - mu) * rin * gwc + gbc + bb(Ab[i]);
            ov[i] = y >= 0.f ? y : 0.01f * y;
        }
        *(float4*)&out[gi]     = make_float4(ov[0], ov[1], ov[2], ov[3]);
        *(float4*)&out[gi + 4] = make_float4(ov[4], ov[5], ov[6], ov[7]);
    }
}

extern "C" void kernel_launch(void* const* d_in, const int* in_sizes, int n_in,
                              void* d_out, int out_size, void* d_ws, size_t ws_size,
                              hipStream_t stream) {
    const float* x      = (const float*)d_in[0];
    const float* Wqkvv  = (const float*)d_in[1];
    // d_in[2] W_out, d_in[3] b_out, d_in[10] index_sample: DEAD in reference
    const float* W_out2 = (const float*)d_in[4];
    const float* b_out2 = (const float*)d_in[5];
    const float* gamma1 = (const float*)d_in[6];
    const float* conv_w = (const float*)d_in[7];
    const float* gn_w   = (const float*)d_in[8];
    const float* gn_b   = (const float*)d_in[9];
    float* out = (float*)d_out;
    float* ws = (float*)d_ws;

    u16*   Tb   = (u16*)(ws + OFF_TB);
    float* SP   = ws + OFF_SP;
    u16*   XCAb = (u16*)(ws + OFF_XCAB);
    u16*   Pk   = (u16*)(ws + OFF_PKB);
    u16*   ATTb = (u16*)(ws + OFF_ATTB);
    u16*   ATTp = (u16*)(ws + OFF_ATTP);
    u16*   WT2  = (u16*)(ws + OFF_WT2);
    u16*   W2B  = (u16*)(ws + OFF_W2B);
    u16*   Wqb  = (u16*)(ws + OFF_WQB);
    u16*   XT   = (u16*)(ws + OFF_XT);
    float* RSQ  = ws + OFF_RSQ;
    float* RED  = ws + OFF_RED;

    k_prep      <<<6857, 256, 0, stream>>>(conv_w, W_out2, Wqkvv, x, WT2, W2B, Wqb, XT, (u32*)ATTp, RSQ, RED);
    k_qkv_mfma  <<<dim3(N_ / 128, 6, B_), 256, 0, stream>>>(Wqb, XT, Tb, RSQ);
    k_ca_score  <<<dim3(8, NH, B_), 256, 0, stream>>>(Tb, SP);
    k_ca_apply  <<<dim3(N_ / 256, NH, B_), 256, 0, stream>>>(Tb, SP, RSQ, XCAb);
    k_out2_mfma <<<dim3(N_ / 64, C_ / 128, B_), 256, 0, stream>>>(W2B, XCAb, b_out2, gamma1, x, ATTb, ATTp);
    k_conv_mfma <<<dim3(N_ / 128, 8, B_), 256, 0, stream>>>(WT2, ATTp, Pk);
    void* gf_args[] = {(void*)&Pk, (void*)&ATTb, (void*)&RED, (void*)&gn_w, (void*)&gn_b, (void*)&out};
    hipLaunchCooperativeKernel((const void*)k_gnfinal, dim3(64, B_), dim3(256), gf_args, 0, stream);
}

// Round 2
// 172.808 us; speedup vs baseline: 1.2335x; 1.2335x over previous
//
#include <hip/hip_runtime.h>
#include <hip/hip_bf16.h>
#include <stdint.h>

// B=2, C=256, H=W=D=16 -> N=4096, nh=8, dh=32. ALL float32 I/O.
// Reference dead code: x_sa path (top-k, index_sample, W_out, b_out, v_sa) — epa = x_ca only.
// Round 9: keep conv split-K=4 (512 blocks = exact 2/CU) and out2 retile 128co x 64n
// (256 blocks = exact 1/CU); REVERT cooperative fused tail (cost ~+40us in round 8)
// back to k_gn_reduce + k_final, extended to 4 partials. Y re-homed to ATTp region
// (dead after conv) to avoid aliasing Pk partial 3.

#define B_ 2
#define C_ 256
#define N_ 4096
#define NH 8
#define PADV 5832
#define CN  (C_*N_)
#define BCN (B_*CN)

typedef unsigned short u16;
typedef unsigned int   u32;

using frag16 = __attribute__((ext_vector_type(8))) short;
using f32x4  = __attribute__((ext_vector_type(4))) float;

__device__ __forceinline__ u16 f2bf(float f) {
    u32 u = __float_as_uint(f);
    u += 0x7fff + ((u >> 16) & 1);
    return (u16)(u >> 16);
}
__device__ __forceinline__ float bb(u16 h) { return __uint_as_float((u32)h << 16); }
__device__ __forceinline__ void gld16(const void* g, void* l) {
    __builtin_amdgcn_global_load_lds((const __attribute__((address_space(1))) u32*)g,
                                     (__attribute__((address_space(3))) u32*)l, 16, 0, 0);
}
__device__ __forceinline__ int padrow(int n) {
    int z = n >> 8, y = (n >> 4) & 15, x = n & 15;
    return (z + 1) * 324 + (y + 1) * 18 + (x + 1);
}

// ---- workspace (float units)
#define OFF_TB    0            // bf16 [B][768][N]; aliased by PKB after ca_apply
#define OFF_SP    3145728      // fp32 [B][NH][8][1024] score partials (dead after ca_apply)
#define OFF_XCAB  3670016      // bf16 [B][N][C] (dead after out2)
#define OFF_PKB   0            // bf16 [4][B][C][N] conv partials (alias TB/SP/XCAB, all dead)
#define OFF_ATTB  6291456      // bf16 [B][C][N]
#define OFF_ATTP  7340032      // bf16 [B][PADV][C] (dead after conv)
#define OFF_Y     7340032      // bf16 [B][C][N] (alias ATTP, dead after conv)
#define OFF_WT2   8833024      // bf16 [27][co][ci]
#define OFF_W2B   9717760      // bf16 [c][c']
#define OFF_WQB   9750528      // bf16 [j][c], j<768
#define OFF_XT    9848832      // bf16 [B][N][C]
#define OFF_RSQ   10897408     // fp32 [B][512]
#define OFF_RED   10898432     // fp32 [B][64][2]

// ================ merged prep ================
__global__ __launch_bounds__(256) void k_prep(const float* __restrict__ CW, const float* __restrict__ W2,
                                              const float* __restrict__ Wq, const float* __restrict__ X,
                                              u16* __restrict__ WT2, u16* __restrict__ W2B,
                                              u16* __restrict__ Wqb, u16* __restrict__ XT,
                                              u32* __restrict__ APz, float* __restrict__ RSQ) {
    __shared__ __align__(16) float ls[6912];
    float (*ts)[33] = (float(*)[33])ls;
    float (*t64)[65] = (float(*)[65])ls;
    int blk = blockIdx.x, tid = threadIdx.x;
    if (blk < 256) {                                    // WT2[t][co][ci] = conv_w[co][ci][t]
        int co = blk;
        const float* src = CW + (size_t)co * 6912;
        for (int u = tid; u < 6912; u += 256) ls[u] = src[u];
        __syncthreads();
#pragma unroll
        for (int t = 0; t < 27; ++t)
            WT2[(((size_t)t * 256 + co) << 8) + tid] = f2bf(ls[tid * 27 + t]);
    } else if (blk < 320) {                             // W2B[c][p] = W2[p][c]
        int bi = blk - 256; int c0 = (bi & 7) * 32, p0 = (bi >> 3) * 32;
        int tx = tid & 31, ty = tid >> 5;
#pragma unroll
        for (int i = 0; i < 4; ++i) ts[ty + i * 8][tx] = W2[(size_t)(p0 + ty + i * 8) * 256 + c0 + tx];
        __syncthreads();
#pragma unroll
        for (int i = 0; i < 4; ++i) W2B[(size_t)(c0 + ty + i * 8) * 256 + p0 + tx] = f2bf(ts[tx][ty + i * 8]);
    } else if (blk < 512) {                             // Wqb[j][c] = Wq[c][j], j<768
        int bi = blk - 320; int c0 = (bi & 7) * 32, j0 = (bi >> 3) * 32;
        int tx = tid & 31, ty = tid >> 5;
#pragma unroll
        for (int i = 0; i < 4; ++i) ts[ty + i * 8][tx] = Wq[(size_t)(c0 + ty + i * 8) * 1024 + j0 + tx];
        __syncthreads();
#pragma unroll
        for (int i = 0; i < 4; ++i) Wqb[(size_t)(j0 + ty + i * 8) * 256 + c0 + tx] = f2bf(ts[tx][ty + i * 8]);
    } else if (blk < 1024) {                            // XT[b][n][c] = x[b][c][n], 64x64 tiles
        int idx = blk - 512;
        int n0 = (idx & 63) * 64, c0 = ((idx >> 6) & 3) * 64, b = idx >> 8;
        int tn = tid & 63, tc4 = tid >> 6;
        const float* Xb = X + (size_t)b * CN;
#pragma unroll
        for (int i = 0; i < 16; ++i) t64[tc4 + i * 4][tn] = Xb[(size_t)(c0 + tc4 + i * 4) * N_ + n0 + tn];
        __syncthreads();
        u16* Xo = XT + (size_t)b * N_ * C_;
#pragma unroll
        for (int i = 0; i < 16; ++i)
            Xo[(size_t)(n0 + tc4 + i * 4) * C_ + c0 + tn] = f2bf(t64[tn][tc4 + i * 4]);
    } else if (blk < 6856) {                            // zero ATTp
        APz[(size_t)(blk - 1024) * 256 + tid] = 0;
    } else {                                            // zero RSQ
        ((float4*)RSQ)[tid] = make_float4(0.f, 0.f, 0.f, 0.f);
    }
}

// ================ QKV MFMA, K=64 chunks + RSQ row-sumsq atomics ================
__global__ __launch_bounds__(256) void k_qkv_mfma(const u16* __restrict__ Wqb, const u16* __restrict__ XT,
                                                  u16* __restrict__ Tb, float* __restrict__ RSQ) {
    __shared__ __align__(16) u16 As[2][8192], Bs[2][8192];
    int n0 = blockIdx.x * 128, j0 = blockIdx.y * 128, b = blockIdx.z;
    int tid = threadIdx.x, lane = tid & 63, w = tid >> 6;
    int wm = w & 1, wn = w >> 1, qm = lane >> 4, lm = lane & 15;
    int srow = lane >> 3;
    int sperm = (((lane & 7) ^ srow) << 3);
    const u16* aB = Wqb + ((size_t)(j0 + w * 32 + srow) << 8) + sperm;
    const u16* bB = XT + ((size_t)(b * N_ + n0 + w * 32 + srow) << 8) + sperm;
    int rdp = ((lm & 7) << 3);
    f32x4 acc[4][4] = {};
    auto stg = [&](int p, int kc) {
#pragma unroll
        for (int i = 0; i < 4; ++i) {
            gld16(aB + i * 2048 + kc * 64, &As[p][w * 2048 + i * 512]);
            gld16(bB + i * 2048 + kc * 64, &Bs[p][w * 2048 + i * 512]);
        }
    };
    stg(0, 0);
#pragma unroll
    for (int kt = 0; kt < 4; ++kt) {
        int p = kt & 1;
        __syncthreads();
        if (kt < 3) stg(p ^ 1, kt + 1);
#pragma unroll
        for (int c2 = 0; c2 < 2; ++c2) {
            frag16 af[4], bf[4];
#pragma unroll
            for (int i = 0; i < 4; ++i)
                af[i] = *(const frag16*)&As[p][(wm * 64 + i * 16 + lm) * 64 + ((((c2 * 4 + qm) << 3) ^ rdp))];
#pragma unroll
            for (int j = 0; j < 4; ++j)
                bf[j] = *(const frag16*)&Bs[p][(wn * 64 + j * 16 + lm) * 64 + ((((c2 * 4 + qm) << 3) ^ rdp))];
#pragma unroll
            for (int i = 0; i < 4; ++i)
#pragma unroll
                for (int j = 0; j < 4; ++j)
                    acc[i][j] = __builtin_amdgcn_mfma_f32_16x16x32_bf16(af[i], bf[j], acc[i][j], 0, 0, 0);
        }
    }
    u16* To = Tb + ((size_t)b * 768 + j0 + wm * 64) * N_ + n0 + wn * 64;
#pragma unroll
    for (int i = 0; i < 4; ++i)
#pragma unroll
        for (int j = 0; j < 4; ++j)
#pragma unroll
            for (int r = 0; r < 4; ++r)
                To[(size_t)(i * 16 + qm * 4 + r) * N_ + j * 16 + lm] = f2bf(acc[i][j][r]);
    if (j0 < 512) {
#pragma unroll
        for (int i = 0; i < 4; ++i)
#pragma unroll
            for (int r = 0; r < 4; ++r) {
                float s = 0.f;
#pragma unroll
                for (int j = 0; j < 4; ++j) s += acc[i][j][r] * acc[i][j][r];
                s += __shfl_xor(s, 1); s += __shfl_xor(s, 2);
                s += __shfl_xor(s, 4); s += __shfl_xor(s, 8);
                if (lm == 0)
                    atomicAdd(&RSQ[b * 512 + j0 + wm * 64 + i * 16 + qm * 4 + r], s);
            }
    }
}

// ================ CA scores via MFMA: SP[b][h][ks][d*32+e] = sum_{k in slice} q[d][k] k[e][k] =====
__global__ __launch_bounds__(256) void k_ca_score(const u16* __restrict__ Tb, float* __restrict__ SP) {
    __shared__ __align__(16) u16 Qs[2][8192], Ks[2][8192];   // 32 rows x 256 u16, XOR-swizzled chunks
    int ks = blockIdx.x, h = blockIdx.y, b = blockIdx.z;
    int tid = threadIdx.x, lane = tid & 63, w = tid >> 6;
    int wm = w & 1, wn = w >> 1, qm = lane >> 4, lm = lane & 15;
    const u16* Qb = Tb + ((size_t)b * 768 + h * 32) * N_;
    const u16* Kb = Tb + ((size_t)b * 768 + 256 + h * 32) * N_;
    int k0base = ks * 512;
    auto stg = [&](int p, int ck) {
        int k0 = k0base + ck * 256;
#pragma unroll
        for (int ri = 0; ri < 4; ++ri) {
            int row = ri * 8 + w * 2 + (lane >> 5);
            int cg = (lane & 31) ^ (row & 31);
            gld16(Qb + (size_t)row * N_ + k0 + cg * 8, &Qs[p][ri * 2048 + w * 512]);
            gld16(Kb + (size_t)row * N_ + k0 + cg * 8, &Ks[p][ri * 2048 + w * 512]);
        }
    };
    f32x4 acc = {};
    stg(0, 0);
#pragma unroll
    for (int ck = 0; ck < 2; ++ck) {
        int p = ck & 1;
        __syncthreads();
        if (ck < 1) stg(p ^ 1, ck + 1);
        int rowA = wm * 16 + lm, rowB = wn * 16 + lm;
#pragma unroll
        for (int kk = 0; kk < 8; ++kk) {
            int slotA = ((kk * 4 + qm) ^ (rowA & 31)) << 3;
            int slotB = ((kk * 4 + qm) ^ (rowB & 31)) << 3;
            frag16 af = *(const frag16*)&Qs[p][rowA * 256 + slotA];
            frag16 bf = *(const frag16*)&Ks[p][rowB * 256 + slotB];
            acc = __builtin_amdgcn_mfma_f32_16x16x32_bf16(af, bf, acc, 0, 0, 0);
        }
    }
    float* o = SP + (((size_t)(b * NH + h)) * 8 + ks) * 1024;
#pragma unroll
    for (int r = 0; r < 4; ++r)
        o[(wm * 16 + qm * 4 + r) * 32 + wn * 16 + lm] = acc[r];
}

// ================ ca: combine partials, scale by 1/(||q|| ||k||), softmax, apply ================
__global__ __launch_bounds__(256) void k_ca_apply(const u16* __restrict__ Tb, const float* __restrict__ SP,
                                                  const float* __restrict__ RSQ, u16* __restrict__ XCAb) {
    int n0 = blockIdx.x * 256, h = blockIdx.y, b = blockIdx.z;
    __shared__ float raw[1024];
    __shared__ float Ae[32][32];
    __shared__ float sq[32], sk[32];
    int tid = threadIdx.x;
    const float* Sp = SP + ((size_t)(b * NH + h)) * 8192;
    for (int u = tid; u < 1024; u += 256) {
        float v = 0.f;
#pragma unroll
        for (int s = 0; s < 8; ++s) v += Sp[s * 1024 + u];
        raw[u] = v;
    }
    if (tid < 32) {
        sq[tid] = 1.0f / fmaxf(sqrtf(RSQ[b * 512 + h * 32 + tid]), 1e-12f);
        sk[tid] = 1.0f / fmaxf(sqrtf(RSQ[b * 512 + 256 + h * 32 + tid]), 1e-12f);
    }
    __syncthreads();
    if (tid < 32) {
        float iq = sq[tid];
        float sv[32]; float m = -1e30f;
#pragma unroll
        for (int e = 0; e < 32; ++e) { sv[e] = raw[tid * 32 + e] * iq * sk[e]; m = fmaxf(m, sv[e]); }
        float sm = 0.f;
#pragma unroll
        for (int e = 0; e < 32; ++e) { sv[e] = __expf(sv[e] - m); sm += sv[e]; }
        float rinv = 1.0f / sm;
#pragma unroll
        for (int e = 0; e < 32; ++e) Ae[e][tid] = sv[e] * rinv;
    }
    __syncthreads();
    int n = n0 + tid;
    const u16* V = Tb + ((size_t)b * 768 + 512 + h * 32) * N_ + n;
    float acc[32];
#pragma unroll
    for (int d = 0; d < 32; ++d) acc[d] = 0.f;
#pragma unroll
    for (int e = 0; e < 32; ++e) {
        float v = bb(V[(size_t)e * N_]);
#pragma unroll
        for (int dg = 0; dg < 8; ++dg) {
            float4 a4 = *(const float4*)&Ae[e][dg * 4];
            acc[dg * 4 + 0] += a4.x * v; acc[dg * 4 + 1] += a4.y * v;
            acc[dg * 4 + 2] += a4.z * v; acc[dg * 4 + 3] += a4.w * v;
        }
    }
    u16* o = XCAb + ((size_t)b * N_ + n) * C_ + h * 32;
#pragma unroll
    for (int dg = 0; dg < 8; ++dg) {
        ushort4 pk;
        pk.x = f2bf(acc[dg * 4 + 0]); pk.y = f2bf(acc[dg * 4 + 1]);
        pk.z = f2bf(acc[dg * 4 + 2]); pk.w = f2bf(acc[dg * 4 + 3]);
        *(ushort4*)(o + dg * 4) = pk;
    }
}

// ================ out2 MFMA (128co x 64n tiles, 256 blocks) + residual ================
__global__ __launch_bounds__(256) void k_out2_mfma(const u16* __restrict__ W2B, const u16* __restrict__ XCAb,
                                                   const float* __restrict__ bias2, const float* __restrict__ g1,
                                                   const float* __restrict__ X, u16* __restrict__ ATTb,
                                                   u16* __restrict__ ATTp) {
    __shared__ __align__(16) u16 As[2][8192], Bs[2][4096];
    int n0 = blockIdx.x * 64, c0 = blockIdx.y * 128, b = blockIdx.z;
    int tid = threadIdx.x, lane = tid & 63, w = tid >> 6;
    int wm = w & 1, wn = w >> 1, qm = lane >> 4, lm = lane & 15;
    int srow = lane >> 3;
    int sperm = (((lane & 7) ^ srow) << 3);
    const u16* aB = W2B + ((size_t)(c0 + w * 32 + srow) << 8) + sperm;
    const u16* bB = XCAb + ((size_t)(b * N_ + n0 + w * 16 + srow) << 8) + sperm;
    int rdp = ((lm & 7) << 3);
    f32x4 acc[4][2] = {};
    auto stg = [&](int p, int kc) {
#pragma unroll
        for (int i = 0; i < 4; ++i)
            gld16(aB + i * 2048 + kc * 64, &As[p][w * 2048 + i * 512]);
#pragma unroll
        for (int i = 0; i < 2; ++i)
            gld16(bB + i * 2048 + kc * 64, &Bs[p][w * 1024 + i * 512]);
    };
    stg(0, 0);
#pragma unroll
    for (int kt = 0; kt < 4; ++kt) {
        int p = kt & 1;
        __syncthreads();
        if (kt < 3) stg(p ^ 1, kt + 1);
#pragma unroll
        for (int c2 = 0; c2 < 2; ++c2) {
            frag16 af[4], bf[2];
#pragma unroll
            for (int i = 0; i < 4; ++i)
                af[i] = *(const frag16*)&As[p][(wm * 64 + i * 16 + lm) * 64 + ((((c2 * 4 + qm) << 3) ^ rdp))];
#pragma unroll
            for (int j = 0; j < 2; ++j)
                bf[j] = *(const frag16*)&Bs[p][(wn * 32 + j * 16 + lm) * 64 + ((((c2 * 4 + qm) << 3) ^ rdp))];
#pragma unroll
            for (int i = 0; i < 4; ++i)
#pragma unroll
                for (int j = 0; j < 2; ++j)
                    acc[i][j] = __builtin_amdgcn_mfma_f32_16x16x32_bf16(af[i], bf[j], acc[i][j], 0, 0, 0);
        }
    }
    int c_base = c0 + wm * 64, n_base = n0 + wn * 32;
    const float* xin = X + (size_t)b * CN;
    u16* Ao = ATTb + (size_t)b * CN;
    u16* Ap = ATTp + ((size_t)b * PADV << 8);
    float val[4][2][4];
#pragma unroll
    for (int i = 0; i < 4; ++i)
#pragma unroll
        for (int r = 0; r < 4; ++r) {
            int c = c_base + i * 16 + qm * 4 + r;
            float gv = g1[c], bi = bias2[c];
#pragma unroll
            for (int j = 0; j < 2; ++j) {
                int n = n_base + j * 16 + lm;
                float v = xin[(size_t)c * N_ + n] + gv * (acc[i][j][r] + bi);
                val[i][j][r] = v;
                Ao[(size_t)c * N_ + n] = f2bf(v);
            }
        }
#pragma unroll
    for (int j = 0; j < 2; ++j) {
        int n = n_base + j * 16 + lm;
        int pr = padrow(n);
#pragma unroll
        for (int i = 0; i < 4; ++i) {
            ushort4 pk;
            pk.x = f2bf(val[i][j][0]); pk.y = f2bf(val[i][j][1]);
            pk.z = f2bf(val[i][j][2]); pk.w = f2bf(val[i][j][3]);
            *(ushort4*)&Ap[((size_t)pr << 8) + c_base + i * 16 + qm * 4] = pk;
        }
    }
}

// ================ conv 3^3 MFMA, split-K=4 (chunk-level tap indexing), 512 blocks ================
__global__ __launch_bounds__(256) void k_conv_mfma(const u16* __restrict__ WT2, const u16* __restrict__ ATTp,
                                                   u16* __restrict__ Pk) {
    __shared__ __align__(16) u16 As[2][8192], Bs[2][8192];
    int n0 = blockIdx.x * 128;
    int co0 = (blockIdx.y & 1) * 128, ks = blockIdx.y >> 1;   // 4 K-slices of 27 chunks each
    int b = blockIdx.z;
    int tid = threadIdx.x, lane = tid & 63, w = tid >> 6;
    int wm = w & 1, wn = w >> 1, qm = lane >> 4, lm = lane & 15;
    int srow = lane >> 3;
    int sperm = (((lane & 7) ^ srow) << 3);
    int ks27 = ks * 27;
    const u16* aB = WT2 + (((size_t)co0 + w * 32 + srow) << 8) + sperm;
    int prA[4];
#pragma unroll
    for (int i = 0; i < 4; ++i) prA[i] = padrow(n0 + w * 32 + i * 8 + srow) << 8;
    const u16* bB = ATTp + ((size_t)b * PADV << 8) + sperm;
    int rdp = ((lm & 7) << 3);
    f32x4 acc[4][4] = {};
    auto stg = [&](int p, int kt) {
        int g = ks27 + kt;                  // global K-chunk in [0,108)
        int tap = g >> 2, kc = g & 3;       // tap in [0,27), 64-wide ci chunk
        int t9 = tap % 9;
        int Koff = (tap / 9 - 1) * 324 + (t9 / 3 - 1) * 18 + (t9 % 3 - 1);
#pragma unroll
        for (int i = 0; i < 4; ++i) {
            gld16(aB + (size_t)tap * 65536 + i * 2048 + kc * 64, &As[p][w * 2048 + i * 512]);
            gld16(bB + prA[i] + Koff * 256 + kc * 64,            &Bs[p][w * 2048 + i * 512]);
        }
    };
    stg(0, 0);
#pragma unroll
    for (int kt = 0; kt < 27; ++kt) {
        int p = kt & 1;
        __syncthreads();
        if (kt < 26) stg(p ^ 1, kt + 1);
#pragma unroll
        for (int c2 = 0; c2 < 2; ++c2) {
            frag16 af[4], bf[4];
#pragma unroll
            for (int i = 0; i < 4; ++i)
                af[i] = *(const frag16*)&As[p][(wm * 64 + i * 16 + lm) * 64 + ((((c2 * 4 + qm) << 3) ^ rdp))];
#pragma unroll
            for (int j = 0; j < 4; ++j)
                bf[j] = *(const frag16*)&Bs[p][(wn * 64 + j * 16 + lm) * 64 + ((((c2 * 4 + qm) << 3) ^ rdp))];
#pragma unroll
            for (int i = 0; i < 4; ++i)
#pragma unroll
                for (int j = 0; j < 4; ++j)
                    acc[i][j] = __builtin_amdgcn_mfma_f32_16x16x32_bf16(af[i], bf[j], acc[i][j], 0, 0, 0);
        }
    }
    u16* Pb = Pk + ((size_t)(ks * B_ + b) * C_ + co0 + wm * 64) * N_ + n0 + wn * 64;
#pragma unroll
    for (int i = 0; i < 4; ++i)
#pragma unroll
        for (int j = 0; j < 4; ++j)
#pragma unroll
            for (int r = 0; r < 4; ++r)
                Pb[(size_t)(i * 16 + qm * 4 + r) * N_ + j * 16 + lm] = f2bf(acc[i][j][r]);
}

// ================ combine bf16 split-K (4 partials) -> bf16 Y + batch mean/var partials ==========
__global__ __launch_bounds__(256) void k_gn_reduce(const u16* __restrict__ Pk, u16* __restrict__ Y,
                                                   float* __restrict__ RED) {
    int blk = blockIdx.x, b = blockIdx.y;
    size_t base = (size_t)b * CN + (size_t)blk * 16384;
    const u16* p0 = Pk + base;
    const u16* p1 = Pk + BCN + base;
    const u16* p2 = Pk + (size_t)2 * BCN + base;
    const u16* p3 = Pk + (size_t)3 * BCN + base;
    u16* y = Y + base;
    float s = 0.f, q = 0.f;
    for (int u = threadIdx.x * 8; u < 16384; u += 2048) {
        uint4 a = *(const uint4*)&p0[u];
        uint4 c1 = *(const uint4*)&p1[u];
        uint4 c2 = *(const uint4*)&p2[u];
        uint4 c3 = *(const uint4*)&p3[u];
        const u16 *A = (const u16*)&a, *B1 = (const u16*)&c1, *C2 = (const u16*)&c2, *D3 = (const u16*)&c3;
        __align__(16) u16 outp[8];
#pragma unroll
        for (int i = 0; i < 8; ++i) {
            float v = bb(A[i]) + bb(B1[i]) + bb(C2[i]) + bb(D3[i]);
            s += v; q += v * v;
            outp[i] = f2bf(v);
        }
        *(uint4*)&y[u] = *(const uint4*)outp;
    }
#pragma unroll
    for (int off = 32; off; off >>= 1) { s += __shfl_down(s, off); q += __shfl_down(q, off); }
    __shared__ float rs_[4], rq[4];
    int lane = threadIdx.x & 63, wv = threadIdx.x >> 6;
    if (!lane) { rs_[wv] = s; rq[wv] = q; }
    __syncthreads();
    if (threadIdx.x == 0) {
        RED[((size_t)b * 64 + blk) * 2 + 0] = rs_[0] + rs_[1] + rs_[2] + rs_[3];
        RED[((size_t)b * 64 + blk) * 2 + 1] = rq[0] + rq[1] + rq[2] + rq[3];
    }
}

// ================ finalize ================
__global__ __launch_bounds__(256) void k_final(const u16* __restrict__ Y, const u16* __restrict__ ATTb,
                                               const float* __restrict__ RED, const float* __restrict__ gw,
                                               const float* __restrict__ gb, float* __restrict__ out) {
    int i = blockIdx.x * 256 + threadIdx.x;
    int b = i >> 20;
    int c = (i >> 12) & 255;
    __shared__ float smu[2];
    if (threadIdx.x < 64) {
        float s = RED[((size_t)b * 64 + threadIdx.x) * 2 + 0];
        float q = RED[((size_t)b * 64 + threadIdx.x) * 2 + 1];
#pragma unroll
        for (int off = 32; off; off >>= 1) { s += __shfl_down(s, off); q += __shfl_down(q, off); }
        if (threadIdx.x == 0) {
            float inv = 1.0f / (float)CN;
            float mu = s * inv, var = q * inv - mu * mu;
            smu[0] = mu; smu[1] = rsqrtf(var + 1e-5f);
        }
    }
    __syncthreads();
    float v = (bb(Y[i]) - smu[0]) * smu[1] * gw[c] + gb[c] + bb(ATTb[i]);
    out[i] = v >= 0.f ? v : 0.01f * v;
}

extern "C" void kernel_launch(void* const* d_in, const int* in_sizes, int n_in,
                              void* d_out, int out_size, void* d_ws, size_t ws_size,
                              hipStream_t stream) {
    const float* x      = (const float*)d_in[0];
    const float* Wqkvv  = (const float*)d_in[1];
    // d_in[2] W_out, d_in[3] b_out, d_in[10] index_sample: DEAD in reference
    const float* W_out2 = (const float*)d_in[4];
    const float* b_out2 = (const float*)d_in[5];
    const float* gamma1 = (const float*)d_in[6];
    const float* conv_w = (const float*)d_in[7];
    const float* gn_w   = (const float*)d_in[8];
    const float* gn_b   = (const float*)d_in[9];
    float* out = (float*)d_out;
    float* ws = (float*)d_ws;

    u16*   Tb   = (u16*)(ws + OFF_TB);
    float* SP   = ws + OFF_SP;
    u16*   XCAb = (u16*)(ws + OFF_XCAB);
    u16*   Pk   = (u16*)(ws + OFF_PKB);
    u16*   Y    = (u16*)(ws + OFF_Y);
    u16*   ATTb = (u16*)(ws + OFF_ATTB);
    u16*   ATTp = (u16*)(ws + OFF_ATTP);
    u16*   WT2  = (u16*)(ws + OFF_WT2);
    u16*   W2B  = (u16*)(ws + OFF_W2B);
    u16*   Wqb  = (u16*)(ws + OFF_WQB);
    u16*   XT   = (u16*)(ws + OFF_XT);
    float* RSQ  = ws + OFF_RSQ;
    float* RED  = ws + OFF_RED;

    k_prep      <<<6857, 256, 0, stream>>>(conv_w, W_out2, Wqkvv, x, WT2, W2B, Wqb, XT, (u32*)ATTp, RSQ);
    k_qkv_mfma  <<<dim3(N_ / 128, 6, B_), 256, 0, stream>>>(Wqb, XT, Tb, RSQ);
    k_ca_score  <<<dim3(8, NH, B_), 256, 0, stream>>>(Tb, SP);
    k_ca_apply  <<<dim3(N_ / 256, NH, B_), 256, 0, stream>>>(Tb, SP, RSQ, XCAb);
    k_out2_mfma <<<dim3(N_ / 64, C_ / 128, B_), 256, 0, stream>>>(W2B, XCAb, b_out2, gamma1, x, ATTb, ATTp);
    k_conv_mfma <<<dim3(N_ / 128, 8, B_), 256, 0, stream>>>(WT2, ATTp, Pk);
    k_gn_reduce <<<dim3(64, B_), 256, 0, stream>>>(Pk, Y, RED);
    k_final     <<<(B_ * CN) / 256, 256, 0, stream>>>(Y, ATTb, RED, gn_w, gn_b, out);
}